// Round 9
// baseline (412.552 us; speedup 1.0000x reference)
//
#include <hip/hip_runtime.h>
#include <hip/hip_bf16.h>

using bf16 = __hip_bfloat16;
using short8 = __attribute__((ext_vector_type(8))) short;
using f32x4  = __attribute__((ext_vector_type(4))) float;
typedef unsigned int u32;

#define LAT_ 1536

__device__ __forceinline__ void glds16(const bf16* g, bf16* l) {
  __builtin_amdgcn_global_load_lds(
      (const __attribute__((address_space(1))) void*)g,
      (__attribute__((address_space(3))) void*)l, 16, 0, 0);
}
__device__ __forceinline__ float b2f(bf16 x) { return __bfloat162float(x); }
__device__ __forceinline__ bf16 f2b(float x) { return __float2bfloat16(x); }

// ---------------- NCHW fp32 -> NHWC bf16 tile ----------------
template<int C, int W>
__device__ __forceinline__ void trans_tile(const float* __restrict__ src, bf16* __restrict__ dst,
                                           int b, int hw0, int c0, bf16 (*tile)[72], int t) {
  constexpr int HW = W * W;
  {
    int cl = t >> 2, h0 = (t & 3) * 16;
    const float* sp = src + (long)(b * C + c0 + cl) * HW + hw0 + h0;
    #pragma unroll
    for (int k = 0; k < 16; k += 4) {
      float4 v = *(const float4*)(sp + k);
      tile[h0 + k + 0][cl] = f2b(v.x);
      tile[h0 + k + 1][cl] = f2b(v.y);
      tile[h0 + k + 2][cl] = f2b(v.z);
      tile[h0 + k + 3][cl] = f2b(v.w);
    }
  }
  __syncthreads();
  {
    int hwl = t >> 2, cc = (t & 3) * 16;
    bf16* dp = dst + ((long)b * HW + hw0 + hwl) * C + c0 + cc;
    #pragma unroll
    for (int k = 0; k < 16; k += 2) {
      __hip_bfloat162 pr;
      pr.x = tile[hwl][cc + k];
      pr.y = tile[hwl][cc + k + 1];
      *(__hip_bfloat162*)(dp + k) = pr;
    }
  }
}

// ---------------- fused prep ----------------
// [0,18432) packA | [18432,18560) pow | [18560,18576) T5 | [18576,18578) bn
// [18578,18586) u | [18586] gconst | [18587,18619) gacc=0 | [18619,18747) V
// [18747] pconst | [18748,21756) transposes
__global__ __launch_bounds__(256) void prep_k(
    const float* __restrict__ g_iw, const float* __restrict__ p_iw,
    const float* __restrict__ p_cw, const float* __restrict__ p_ow, const float* __restrict__ f5,
    const float* __restrict__ g_bg, const float* __restrict__ g_bb, const float* __restrict__ g_bm,
    const float* __restrict__ g_bv, const float* __restrict__ p_bg, const float* __restrict__ p_bb,
    const float* __restrict__ p_bm, const float* __restrict__ p_bv,
    const float* __restrict__ g_ib, const float* __restrict__ p_ib, const float* __restrict__ p_cb,
    const float* __restrict__ p_ob,
    const float* __restrict__ g_ow, const float* __restrict__ g_cw,
    const float* __restrict__ g_cb, const float* __restrict__ g_ob,
    const float* __restrict__ f0, const float* __restrict__ f1, const float* __restrict__ f2,
    const float* __restrict__ f3, const float* __restrict__ f4,
    bf16* __restrict__ Wp, bf16* __restrict__ pow16, bf16* __restrict__ V16,
    bf16* __restrict__ T5, float* __restrict__ bnp, float* __restrict__ u,
    float* __restrict__ gacc,
    bf16* __restrict__ T0, bf16* __restrict__ T1, bf16* __restrict__ T2,
    bf16* __restrict__ T3, bf16* __restrict__ T4) {
  __shared__ bf16 tile[64][72];
  __shared__ float red[256];
  int B = blockIdx.x, t = threadIdx.x;
  if (B < 18432) {
    int seg = B / 3072;
    int idx = (B % 3072) * 256 + t;
    if (idx < 512 * 1536) {
      int r = idx / 1536, c = idx % 1536;
      const float* src; int co;
      switch (seg) {
        case 0: src = g_iw; co = 0;    break;
        case 1: src = g_iw; co = 1536; break;
        case 2: src = p_iw; co = 0;    break;
        case 3: src = p_iw; co = 1536; break;
        case 4: src = g_iw; co = 3072; break;
        default: src = p_iw; co = 3072; break;
      }
      Wp[(long)seg * 512 * 1536 + idx] = f2b(src[(long)r * 4608 + co + c]);
    }
    return;
  }
  if (B < 18560) { int idx = (B - 18432) * 256 + t; pow16[idx] = f2b(p_ow[idx]); return; }
  if (B < 18576) { int idx = (B - 18560) * 256 + t; T5[idx] = f2b(f5[idx]); return; }
  if (B < 18578) {
    int k = (B - 18576) * 256 + t;
    if (k < 512) {
      float sg = g_bg[k] / sqrtf(g_bv[k] + 1e-5f);
      bnp[k] = sg; bnp[512 + k] = g_bb[k] - g_bm[k] * sg;
      float sp = p_bg[k] / sqrtf(p_bv[k] + 1e-5f);
      bnp[1024 + k] = sp; bnp[1536 + k] = p_bb[k] - p_bm[k] * sp;
      bnp[2048 + k] = g_ib[k]; bnp[2560 + k] = p_ib[k];
    }
    return;
  }
  if (B < 18586) {                      // u[k] = sum_o g_ow[o]*g_cw[o*512+k]
    __shared__ float ured[4][64];
    int k0 = (B - 18578) * 64;
    int kk = t & 63, part = t >> 6;
    int k = k0 + kk;
    float s = 0.f;
    for (int o = part * 128; o < part * 128 + 128; ++o)
      s = fmaf(g_ow[o], g_cw[o * 512 + k], s);
    ured[part][kk] = s;
    __syncthreads();
    if (part == 0) u[k] = ured[0][kk] + ured[1][kk] + ured[2][kk] + ured[3][kk];
    return;
  }
  if (B == 18586) {                     // gconst
    red[t] = g_ow[t] * g_cb[t] + g_ow[t + 256] * g_cb[t + 256];
    __syncthreads();
    for (int off = 128; off; off >>= 1) {
      if (t < off) red[t] += red[t + off];
      __syncthreads();
    }
    if (t == 0) bnp[3072] = red[0] + g_ob[0];
    return;
  }
  if (B < 18619) { int idx = (B - 18587) * 256 + t; gacc[idx] = 0.f; return; }
  if (B < 18747) {                      // V[c][k] = sum_n p_ow[c][n]*p_cw[n][k]
    int idx = (B - 18619) * 256 + t;
    int c = idx >> 9, k = idx & 511;
    float s = 0.f;
    for (int nn = 0; nn < 512; ++nn)
      s = fmaf(p_ow[c * 512 + nn], p_cw[nn * 512 + k], s);
    V16[idx] = f2b(s);
    return;
  }
  if (B == 18747) {                     // pconst[c] = p_ob[c] + sum p_ow[c][n]*p_cb[n]
    if (t < 64) {
      float s = p_ob[t];
      for (int nn = 0; nn < 512; ++nn) s = fmaf(p_ow[t * 512 + nn], p_cb[nn], s);
      bnp[3104 + t] = s;
    }
    return;
  }
  {
    int q = B - 18748;
    int b = q / 376, tt = q % 376;
    if (tt < 256)      trans_tile<64, 128>(f0, T0, b, tt * 64, 0, tile, t);
    else if (tt < 320) trans_tile<64, 64 >(f1, T1, b, (tt - 256) * 64, 0, tile, t);
    else if (tt < 352) { int z = tt - 320; trans_tile<128, 32>(f2, T2, b, (z & 15) * 64, (z >> 4) * 64, tile, t); }
    else if (tt < 368) { int z = tt - 352; trans_tile<256, 16>(f3, T3, b, (z & 3) * 64, (z >> 2) * 64, tile, t); }
    else               { int z = tt - 368; trans_tile<512, 8 >(f4, T4, b, 0, z * 64, tile, t); }
  }
}

// ---------------- sampling ----------------
__device__ __forceinline__ float blo(u32 r) { return __uint_as_float(r << 16); }
__device__ __forceinline__ float bhi(u32 r) { return __uint_as_float(r & 0xffff0000u); }

template<int C, int W>
__device__ __forceinline__ void proc2(const bf16* __restrict__ T, int b,
    const float* MX, const float* MY, bf16* __restrict__ Sb, int koff, int t) {
  constexpr int C2 = C / 2, HW = W * W;
  const bf16* Tb = T + (long)b * HW * C;
  for (int idx = t; idx < 16 * C2; idx += 256) {
    int q = idx / C2, c2 = idx % C2;
    float x = MX[q], y = MY[q];
    float fx = fminf(fmaxf(x * ((float)W / 256.f) - 0.5f, 0.f), (float)(W - 1));
    float fy = fminf(fmaxf(y * ((float)W / 256.f) - 0.5f, 0.f), (float)(W - 1));
    float x0f = floorf(fx), y0f = floorf(fy);
    float wx = fx - x0f, wy = fy - y0f;
    int x0 = (int)x0f, y0 = (int)y0f;
    int x1 = min(x0 + 1, W - 1), y1 = min(y0 + 1, W - 1);
    u32 r00 = *(const u32*)&Tb[(y0 * W + x0) * C + 2 * c2];
    u32 r01 = *(const u32*)&Tb[(y0 * W + x1) * C + 2 * c2];
    u32 r10 = *(const u32*)&Tb[(y1 * W + x0) * C + 2 * c2];
    u32 r11 = *(const u32*)&Tb[(y1 * W + x1) * C + 2 * c2];
    float w00 = (1.f - wx) * (1.f - wy), w01 = wx * (1.f - wy);
    float w10 = (1.f - wx) * wy,        w11 = wx * wy;
    float vlo = blo(r00) * w00 + blo(r01) * w01 + blo(r10) * w10 + blo(r11) * w11;
    float vhi = bhi(r00) * w00 + bhi(r01) * w01 + bhi(r10) * w10 + bhi(r11) * w11;
    __hip_bfloat162 pr;
    pr.x = f2b(vlo); pr.y = f2b(vhi);
    *(__hip_bfloat162*)&Sb[(long)q * LAT_ + koff + 2 * c2] = pr;
  }
}

__global__ __launch_bounds__(256) void sample5_k(
    const bf16* __restrict__ T0, const bf16* __restrict__ T1, const bf16* __restrict__ T2,
    const bf16* __restrict__ T3, const bf16* __restrict__ T4, const bf16* __restrict__ T5,
    const float* __restrict__ P, bf16* __restrict__ Sball) {
  int b = blockIdx.z, p0 = blockIdx.x * 16, lvl = blockIdx.y, t = threadIdx.x;
  __shared__ float Px[32], Py[32], MX[16], MY[16];
  if (t < 32) { Px[t] = P[(b * 32 + t) * 2]; Py[t] = P[(b * 32 + t) * 2 + 1]; }
  __syncthreads();
  if (t < 16) {
    int m = p0 + t;
    float x, y;
    if (m < 32) { x = Px[m]; y = Py[m]; }
    else { int ij = m - 32, i = ij >> 5, j = ij & 31;
           x = 0.5f * (Px[i] + Px[j]); y = 0.5f * (Py[i] + Py[j]); }
    MX[t] = x; MY[t] = y;
  }
  __syncthreads();
  bf16* Sb = Sball + ((long)b * 1056 + p0) * LAT_;
  switch (lvl) {
    case 0: proc2<64, 128>(T0, b, MX, MY, Sb, 0,    t); break;
    case 1: proc2<64, 64 >(T1, b, MX, MY, Sb, 64,   t); break;
    case 2: proc2<128, 32>(T2, b, MX, MY, Sb, 128,  t); break;
    case 3: proc2<256, 16>(T3, b, MX, MY, Sb, 256,  t); break;
    case 4: proc2<512, 8 >(T4, b, MX, MY, Sb, 512,  t); break;
    default:
      for (int idx = t; idx < 16 * 256; idx += 256) {
        int q = idx >> 8, c2 = idx & 255;
        *(__hip_bfloat162*)&Sb[(long)q * LAT_ + 1024 + 2 * c2] =
            *(const __hip_bfloat162*)&T5[b * 512 + 2 * c2];
      }
  }
}

// ---------------- node GEMM (batch-looped weight reuse): A4[b][32][2048] ----------------
__global__ __launch_bounds__(256) void nodegemm_k(
    const bf16* __restrict__ Sball, const bf16* __restrict__ Wp, float* __restrict__ A4) {
  int n0 = blockIdx.x * 64;
  int t = threadIdx.x, w = t >> 6, lane = t & 63;
  int nn = n0 + w * 16;
  int frow = lane & 15, fko = (lane >> 4) * 8;
  f32x4 acc[8][2] = {};
  for (int kb = 0; kb < LAT_; kb += 32) {
    short8 bq = *(const short8*)&Wp[(long)(nn + frow) * LAT_ + kb + fko];
    #pragma unroll
    for (int b = 0; b < 8; ++b) {
      const bf16* Ab = Sball + (long)b * 1056 * LAT_;
      #pragma unroll
      for (int i = 0; i < 2; ++i) {
        short8 aq = *(const short8*)&Ab[(long)(i * 16 + frow) * LAT_ + kb + fko];
        acc[b][i] = __builtin_amdgcn_mfma_f32_16x16x32_bf16(aq, bq, acc[b][i], 0, 0, 0);
      }
    }
  }
  #pragma unroll
  for (int b = 0; b < 8; ++b)
    #pragma unroll
    for (int i = 0; i < 2; ++i)
      #pragma unroll
      for (int r = 0; r < 4; ++r) {
        int m = i * 16 + (lane >> 4) * 4 + r;
        int n = nn + (lane & 15);
        A4[(long)b * 65536 + m * 2048 + n] = acc[b][i][r];
      }
}

// ---------------- edge GEMM: M=1024, N=1024 (g|p), K=1536 ----------------
__global__ __launch_bounds__(256) void edge_k(
    const bf16* __restrict__ Sball, const bf16* __restrict__ WpE,
    const float* __restrict__ bnp, const float* __restrict__ A4,
    const float* __restrict__ u, const float* __restrict__ g_ow,
    bf16* __restrict__ XFh, bf16* __restrict__ DH, float* __restrict__ gacc) {
  int b = blockIdx.z;
  int m0 = blockIdx.x * 128, n0 = blockIdx.y * 128;
  const bf16* A = Sball + (long)b * 1056 * LAT_ + 32 * LAT_;
  __shared__ bf16 Ash[128 * 32];
  __shared__ bf16 Bsh[128 * 32];
  int t = threadIdx.x, w = t >> 6, lane = t & 63;
  int mh = (w & 1) * 64, nh = (w >> 1) * 64;
  int frow = lane & 15, fko = (lane >> 4) * 8;
  int lrow = lane >> 2, lchunk = lane & 3;
  f32x4 acc[4][4] = {};
  for (int kb = 0; kb < LAT_; kb += 32) {
    #pragma unroll
    for (int q = 0; q < 2; ++q) {
      int ra = q * 64 + w * 16 + lrow;
      glds16(&A[(long)(m0 + ra) * LAT_ + kb + lchunk * 8],   &Ash[ra * 32 + lchunk * 8]);
      glds16(&WpE[(long)(n0 + ra) * LAT_ + kb + lchunk * 8], &Bsh[ra * 32 + lchunk * 8]);
    }
    __syncthreads();
    short8 af[4], bq[4];
    #pragma unroll
    for (int i = 0; i < 4; ++i) af[i] = *(const short8*)&Ash[(mh + i * 16 + frow) * 32 + fko];
    #pragma unroll
    for (int j = 0; j < 4; ++j) bq[j] = *(const short8*)&Bsh[(nh + j * 16 + frow) * 32 + fko];
    #pragma unroll
    for (int i = 0; i < 4; ++i)
      #pragma unroll
      for (int j = 0; j < 4; ++j)
        acc[i][j] = __builtin_amdgcn_mfma_f32_16x16x32_bf16(af[i], bq[j], acc[i][j], 0, 0, 0);
    __syncthreads();
  }
  if (n0 < 512) {                                     // gate half
    float pg[16];
    #pragma unroll
    for (int z = 0; z < 16; ++z) pg[z] = 0.f;
    #pragma unroll
    for (int i = 0; i < 4; ++i) {
      #pragma unroll
      for (int j = 0; j < 4; ++j) {
        int n = n0 + nh + j * 16 + (lane & 15);
        float gw = g_ow[n], uu = u[n];
        float sc = bnp[n], sh = bnp[512 + n], ib = bnp[2048 + n];
        #pragma unroll
        for (int r = 0; r < 4; ++r) {
          int m = m0 + mh + i * 16 + (lane >> 4) * 4 + r;
          float v = acc[i][j][r] + ib
                  + A4[((long)b * 32 + (m >> 5)) * 2048 + n]
                  + A4[((long)b * 32 + (m & 31)) * 2048 + 512 + n];
          float d = fmaxf(fmaf(v, sc, sh), 0.f);
          pg[i * 4 + r] += gw * v + uu * d;
        }
      }
    }
    #pragma unroll
    for (int z = 0; z < 16; ++z) {
      float v = pg[z];
      v += __shfl_xor(v, 1, 16);
      v += __shfl_xor(v, 2, 16);
      v += __shfl_xor(v, 4, 16);
      v += __shfl_xor(v, 8, 16);
      pg[z] = v;
    }
    if ((lane & 15) == 0) {
      #pragma unroll
      for (int z = 0; z < 16; ++z) {
        int m = m0 + mh + (z >> 2) * 16 + (lane >> 4) * 4 + (z & 3);
        atomicAdd(&gacc[(long)b * 1024 + m], pg[z]);
      }
    }
  } else {                                            // p half: store compact
    #pragma unroll
    for (int i = 0; i < 4; ++i) {
      #pragma unroll
      for (int j = 0; j < 4; ++j) {
        int n = n0 + nh + j * 16 + (lane & 15);
        int np = n - 512;
        float sc = bnp[1024 + np], sh = bnp[1536 + np], ib = bnp[2048 + n];
        #pragma unroll
        for (int r = 0; r < 4; ++r) {
          int m = m0 + mh + i * 16 + (lane >> 4) * 4 + r;
          float v = acc[i][j][r] + ib
                  + A4[((long)b * 32 + (m >> 5)) * 2048 + 1024 + np]
                  + A4[((long)b * 32 + (m & 31)) * 2048 + 1536 + np];
          long e = ((long)b * 1024 + m) * 512 + np;
          XFh[e] = f2b(v);
          DH[e]  = f2b(fmaxf(fmaf(v, sc, sh), 0.f));
        }
      }
    }
  }
}

// ---------------- post: PR = pow@XFh + V@DH + pconst, then gate/norm/mask/store ----------------
__global__ __launch_bounds__(256) void post_k(
    const bf16* __restrict__ XFh, const bf16* __restrict__ DH,
    const bf16* __restrict__ pow16, const bf16* __restrict__ V16,
    const float* __restrict__ bnp, const float* __restrict__ gacc,
    const int* __restrict__ nvec, float* __restrict__ out) {
  int b = blockIdx.y;
  int m0 = blockIdx.x * 128;
  __shared__ float smem_f[128 * 65];           // aliased: staging (24.5 KB) then ol (33.3 KB)
  bf16* Xsh = (bf16*)smem_f;                   // 128*32
  bf16* Dsh = Xsh + 4096;                      // 128*32
  bf16* Psh = Xsh + 8192;                      // 64*32
  bf16* Vsh = Xsh + 10240;                     // 64*32
  float (*ol)[65] = (float(*)[65])smem_f;
  int t = threadIdx.x, w = t >> 6, lane = t & 63;
  int mh = w * 32;
  int frow = lane & 15, fko = (lane >> 4) * 8;
  int lrow = lane >> 2, lchunk = lane & 3;
  const bf16* Xa = XFh + (long)b * 1024 * 512;
  const bf16* Da = DH + (long)b * 1024 * 512;
  f32x4 acc[2][4] = {};
  for (int kb = 0; kb < 512; kb += 32) {
    #pragma unroll
    for (int q = 0; q < 2; ++q) {
      int ra = mh + q * 16 + lrow;
      glds16(&Xa[(long)(m0 + ra) * 512 + kb + lchunk * 8], &Xsh[ra * 32 + lchunk * 8]);
      glds16(&Da[(long)(m0 + ra) * 512 + kb + lchunk * 8], &Dsh[ra * 32 + lchunk * 8]);
    }
    {
      int rb = w * 16 + lrow;
      glds16(&pow16[(long)rb * 512 + kb + lchunk * 8], &Psh[rb * 32 + lchunk * 8]);
      glds16(&V16[(long)rb * 512 + kb + lchunk * 8],   &Vsh[rb * 32 + lchunk * 8]);
    }
    __syncthreads();
    short8 ax[2], ad[2], bp[4], bv[4];
    #pragma unroll
    for (int i = 0; i < 2; ++i) {
      ax[i] = *(const short8*)&Xsh[(mh + i * 16 + frow) * 32 + fko];
      ad[i] = *(const short8*)&Dsh[(mh + i * 16 + frow) * 32 + fko];
    }
    #pragma unroll
    for (int j = 0; j < 4; ++j) {
      bp[j] = *(const short8*)&Psh[(j * 16 + frow) * 32 + fko];
      bv[j] = *(const short8*)&Vsh[(j * 16 + frow) * 32 + fko];
    }
    #pragma unroll
    for (int i = 0; i < 2; ++i)
      #pragma unroll
      for (int j = 0; j < 4; ++j) {
        acc[i][j] = __builtin_amdgcn_mfma_f32_16x16x32_bf16(ax[i], bp[j], acc[i][j], 0, 0, 0);
        acc[i][j] = __builtin_amdgcn_mfma_f32_16x16x32_bf16(ad[i], bv[j], acc[i][j], 0, 0, 0);
      }
    __syncthreads();
  }
  // epilogue: bias, norm, gate, mask
  float val[2][4][4], ssl[2][4];
  #pragma unroll
  for (int i = 0; i < 2; ++i)
    #pragma unroll
    for (int r = 0; r < 4; ++r) ssl[i][r] = 0.f;
  #pragma unroll
  for (int i = 0; i < 2; ++i)
    #pragma unroll
    for (int j = 0; j < 4; ++j) {
      float pc = bnp[3104 + j * 16 + (lane & 15)];
      #pragma unroll
      for (int r = 0; r < 4; ++r) {
        float v = acc[i][j][r] + pc;
        val[i][j][r] = v;
        ssl[i][r] = fmaf(v, v, ssl[i][r]);
      }
    }
  #pragma unroll
  for (int i = 0; i < 2; ++i)
    #pragma unroll
    for (int r = 0; r < 4; ++r) {
      float v = ssl[i][r];
      v += __shfl_xor(v, 1, 16);
      v += __shfl_xor(v, 2, 16);
      v += __shfl_xor(v, 4, 16);
      v += __shfl_xor(v, 8, 16);
      ssl[i][r] = v;
    }
  int nb = nvec[b];
  float gconst = bnp[3072];
  float scale[2][4];
  #pragma unroll
  for (int i = 0; i < 2; ++i)
    #pragma unroll
    for (int r = 0; r < 4; ++r) {
      int m = m0 + mh + i * 16 + (lane >> 4) * 4 + r;
      float gl = gacc[(long)b * 1024 + m] + gconst;
      float gate = 1.f / (1.f + expf(-gl));
      int ii = m >> 5, jj = m & 31;
      float maskv = (ii < nb && jj < nb) ? 1.f : 0.f;
      scale[i][r] = gate * maskv / fmaxf(sqrtf(ssl[i][r]), 1e-12f);
    }
  // transpose via LDS (staging region dead), coalesced store
  #pragma unroll
  for (int i = 0; i < 2; ++i)
    #pragma unroll
    for (int j = 0; j < 4; ++j)
      #pragma unroll
      for (int r = 0; r < 4; ++r)
        ol[mh + i * 16 + (lane >> 4) * 4 + r][j * 16 + (lane & 15)] = val[i][j][r] * scale[i][r];
  __syncthreads();
  {
    int c = t >> 2, ms = (t & 3) * 32;
    float* op = out + ((long)b * 64 + c) * 1024 + m0 + ms;
    #pragma unroll
    for (int k = 0; k < 32; k += 4) {
      float4 v;
      v.x = ol[ms + k + 0][c];
      v.y = ol[ms + k + 1][c];
      v.z = ol[ms + k + 2][c];
      v.w = ol[ms + k + 3][c];
      *(float4*)(op + k) = v;
    }
  }
}

extern "C" void kernel_launch(void* const* d_in, const int* in_sizes, int n_in,
                              void* d_out, int out_size, void* d_ws, size_t ws_size,
                              hipStream_t stream) {
  const float* f0 = (const float*)d_in[0];
  const float* f1 = (const float*)d_in[1];
  const float* f2 = (const float*)d_in[2];
  const float* f3 = (const float*)d_in[3];
  const float* f4 = (const float*)d_in[4];
  const float* f5 = (const float*)d_in[5];
  const float* P  = (const float*)d_in[6];
  const int*   n  = (const int*)d_in[7];
  const float *g_iw=(const float*)d_in[8],  *g_ib=(const float*)d_in[9],
              *g_bg=(const float*)d_in[10], *g_bb=(const float*)d_in[11],
              *g_bm=(const float*)d_in[12], *g_bv=(const float*)d_in[13],
              *g_cw=(const float*)d_in[14], *g_cb=(const float*)d_in[15],
              *g_ow=(const float*)d_in[16], *g_ob=(const float*)d_in[17];
  const float *p_iw=(const float*)d_in[18], *p_ib=(const float*)d_in[19],
              *p_bg=(const float*)d_in[20], *p_bb=(const float*)d_in[21],
              *p_bm=(const float*)d_in[22], *p_bv=(const float*)d_in[23],
              *p_cw=(const float*)d_in[24], *p_cb=(const float*)d_in[25],
              *p_ow=(const float*)d_in[26], *p_ob=(const float*)d_in[27];
  float* out = (float*)d_out;
  char* wsb = (char*)d_ws;

  // workspace (byte offsets)
  bf16*  Sb    = (bf16*)(wsb + 0);            // 25,952,256
  bf16*  Wp    = (bf16*)(wsb + 25952256);     // 9,437,184  -> 35,389,440
  bf16*  pow16 = (bf16*)(wsb + 35389440);     // 65,536     -> 35,454,976
  bf16*  V16   = (bf16*)(wsb + 35454976);     // 65,536     -> 35,520,512
  bf16*  T5    = (bf16*)(wsb + 35520512);     // 8,192      -> 35,528,704
  float* bnp   = (float*)(wsb + 35528704);    // 16,384     -> 35,545,088
  float* u     = (float*)(wsb + 35545088);    // 2,048      -> 35,547,136
  float* gacc  = (float*)(wsb + 35547136);    // 32,768     -> 35,579,904
  float* A4    = (float*)(wsb + 35579904);    // 2,097,152  -> 37,677,056
  bf16*  XFh   = (bf16*)(wsb + 37677056);     // 8,388,608  -> 46,065,664
  bf16*  DH    = (bf16*)(wsb + 46065664);     // 8,388,608  -> 54,454,272
  // T0..T4 overlay XFh/DH + tail (dead until edge_k)
  bf16*  T0 = (bf16*)(wsb + 37677056);        // 16,777,216 -> 54,454,272
  bf16*  T1 = (bf16*)(wsb + 54454272);        // 4,194,304  -> 58,648,576
  bf16*  T2 = (bf16*)(wsb + 58648576);        // 2,097,152  -> 60,745,728
  bf16*  T3 = (bf16*)(wsb + 60745728);        // 1,048,576  -> 61,794,304
  bf16*  T4 = (bf16*)(wsb + 61794304);        //   524,288  -> 62,318,592
  bf16*  WpE = Wp + (long)2048 * LAT_;

  prep_k<<<21756, 256, 0, stream>>>(g_iw, p_iw, p_cw, p_ow, f5,
      g_bg, g_bb, g_bm, g_bv, p_bg, p_bb, p_bm, p_bv, g_ib, p_ib, p_cb, p_ob,
      g_ow, g_cw, g_cb, g_ob, f0, f1, f2, f3, f4,
      Wp, pow16, V16, T5, bnp, u, gacc, T0, T1, T2, T3, T4);
  sample5_k<<<dim3(66, 6, 8), 256, 0, stream>>>(T0, T1, T2, T3, T4, T5, P, Sb);
  nodegemm_k<<<32, 256, 0, stream>>>(Sb, Wp, A4);
  edge_k<<<dim3(8, 8, 8), 256, 0, stream>>>(Sb, WpE, bnp, A4, u, g_ow, XFh, DH, gacc);
  post_k<<<dim3(8, 8), 256, 0, stream>>>(XFh, DH, pow16, V16, bnp, gacc, n, out);
}